// Round 1
// 25046.672 us; speedup vs baseline: 1.6720x; 1.6720x over previous
//
#include <hip/hip_runtime.h>
#include <cstdint>

#define TENC 2048
#define TDEC 256
#define BSZ  128
#define HID  256
#define KEYD 128
#define VALD 128
#define H1D  512
#define N1   2048   // 4*H1D
#define N2   512    // 4*KEYD
#define VOC  1000
#define NPAD 1024
#define NS   16     // attention t-splits (2048/128)
#define KS1  16     // LSTM1 k-splits
#define KC1  56     // 896/16

// ---- workspace layout (float offsets) ----
#define OFF_WT1   0            // 896*2048  k-major [k][n]
#define OFF_WT2   1835008      // 640*512
#define OFF_WLT   2162688      // 256*1024 (n padded to 1024)
#define OFF_B1    2424832      // 2048
#define OFF_B2    2426880      // 512
#define OFF_H1    2427392      // 128*512
#define OFF_C1    2492928      // 128*512
#define OFF_H2    2558464      // 128*128
#define OFF_C2    2574848      // 128*128
#define OFF_P1    2591232      // 16*128*2048 k-split partials LSTM1
#define OFF_AM    6785536      // 128*16 attn local max
#define OFF_AS    6787584      // 128*16 attn local expsum
#define OFF_AP    6789632      // 128*16*128 attn partial ctx
#define OFF_H2H   7051776      // 256*128*128 h2 history
#define OFF_CXH   11246080     // 256*128*128 ctx history
// total 15440384 floats = 61.8 MB

#define PREP_ELEMS 2591232

__device__ __forceinline__ float sigf(float x)   { return 1.0f / (1.0f + __expf(-x)); }
__device__ __forceinline__ float tanhf2(float x) { return 1.0f - 2.0f / (__expf(2.0f * x) + 1.0f); }

// One-time: transpose weights to k-major, fuse biases, zero states.
__global__ __launch_bounds__(256) void prep_kernel(
    const float* __restrict__ Wih1, const float* __restrict__ Whh1,
    const float* __restrict__ bih1, const float* __restrict__ bhh1,
    const float* __restrict__ Wih2, const float* __restrict__ Whh2,
    const float* __restrict__ bih2, const float* __restrict__ bhh2,
    const float* __restrict__ Wlin, float* __restrict__ ws)
{
    int i = blockIdx.x * 256 + threadIdx.x;
    if (i < 1835008) {                       // WT1[k][n]
        int k = i >> 11, n = i & 2047;
        ws[OFF_WT1 + i] = (k < 384) ? Wih1[n * 384 + k] : Whh1[n * 512 + (k - 384)];
        return;
    }
    i -= 1835008;
    if (i < 327680) {                        // WT2[k][n]
        int k = i >> 9, n = i & 511;
        ws[OFF_WT2 + i] = (k < 512) ? Wih2[n * 512 + k] : Whh2[n * 128 + (k - 512)];
        return;
    }
    i -= 327680;
    if (i < 262144) {                        // WlinT[k][n], n padded to 1024
        int k = i >> 10, n = i & 1023;
        ws[OFF_WLT + i] = (n < VOC) ? Wlin[n * 256 + k] : 0.0f;
        return;
    }
    i -= 262144;
    if (i < 2048) { ws[OFF_B1 + i] = bih1[i] + bhh1[i]; return; }
    i -= 2048;
    if (i < 512)  { ws[OFF_B2 + i] = bih2[i] + bhh2[i]; return; }
    i -= 512;
    if (i < 65536) { ws[OFF_H1 + i] = 0.0f; return; }
    i -= 65536;
    if (i < 65536) { ws[OFF_C1 + i] = 0.0f; return; }
    i -= 65536;
    if (i < 16384) { ws[OFF_H2 + i] = 0.0f; return; }
    i -= 16384;
    ws[OFF_C2 + i] = 0.0f;
}

// LSTM1 gates partial GEMM + fused attn-combine prologue (ctx of step t-1).
// Grid 512 blocks x 256. Block B: bq = B>>5 (8 batches), slice = B&31 -> s = slice>>1, half = slice&1.
// bq-major ordering keeps all 16 bq-readers of a weight slice on one XCD (B%8 = slice%8).
__global__ __launch_bounds__(256, 2) void l1A_kernel(
    const float* __restrict__ emb, const int* __restrict__ text,
    float* __restrict__ ws, int t)
{
    __shared__ float s_ms[8][16];
    __shared__ float s_ss[8][16];
    __shared__ __align__(16) float s_ctx[8][128];
    __shared__ __align__(16) float x_lds[KC1][8];
    __shared__ int   s_tok[8];

    int B = blockIdx.x;
    int bq    = B >> 5;
    int slice = B & 31;
    int s  = slice >> 1;
    int hf = slice & 1;
    int tid = threadIdx.x;
    int n4 = hf * 256 + tid;                 // 0..511

    if (tid < 8) s_tok[tid] = text[(bq * 8 + tid) * TDEC + t];

    // ---- ctx combine: merge 16 flash partials from attn1 of step t-1 ----
    if (t > 0) {
        if (tid < 128) {
            int bi = tid >> 4, i = tid & 15;
            s_ms[bi][i] = ws[OFF_AM + (bq * 8 + bi) * NS + i];
        } else {
            int q = tid - 128;
            int bi = q >> 4, i = q & 15;
            s_ss[bi][i] = ws[OFF_AS + (bq * 8 + bi) * NS + i];
        }
        __syncthreads();
        int bi = tid >> 5, d4 = tid & 31;
        float M = -3.4e38f;
        #pragma unroll
        for (int i = 0; i < NS; ++i) M = fmaxf(M, s_ms[bi][i]);
        float Ts = 0.f;
        float4 acc = make_float4(0.f, 0.f, 0.f, 0.f);
        const float* ap = ws + OFF_AP + ((size_t)(bq * 8 + bi) * NS) * 128 + d4 * 4;
        #pragma unroll
        for (int i = 0; i < NS; ++i) {
            float w = __expf(s_ms[bi][i] - M);
            Ts += s_ss[bi][i] * w;
            float4 p = *(const float4*)(ap + i * 128);
            acc.x += w * p.x; acc.y += w * p.y; acc.z += w * p.z; acc.w += w * p.w;
        }
        float inv = 1.0f / Ts;
        acc.x *= inv; acc.y *= inv; acc.z *= inv; acc.w *= inv;
        *(float4*)&s_ctx[bi][d4 * 4] = acc;
        if (slice == 0)   // one designated block per bq writes ctx history
            *(float4*)(ws + OFF_CXH + (((size_t)(t - 1)) * BSZ + bq * 8 + bi) * 128 + d4 * 4) = acc;
    } else {
        *(float4*)&s_ctx[tid >> 5][(tid & 31) * 4] = make_float4(0.f, 0.f, 0.f, 0.f);
    }
    __syncthreads();

    // ---- stage x tile [8 b][56 k] into LDS: emb | ctx | h1 ----
    {
        int k0 = s * KC1;
        for (int slot = tid; slot < KC1 * 8; slot += 256) {
            int kk = slot >> 3, bi = slot & 7;
            int k = k0 + kk;
            float v;
            if (k < 256)      v = emb[s_tok[bi] * HID + k];
            else if (k < 384) v = s_ctx[bi][k - 256];
            else              v = ws[OFF_H1 + (bq * 8 + bi) * H1D + (k - 384)];
            x_lds[kk][bi] = v;
        }
    }
    __syncthreads();

    // ---- main GEMM: 8 b x 4 n over 56 k ----
    const float* wp = ws + OFF_WT1 + (size_t)(s * KC1) * N1 + n4 * 4;
    float4 a[8];
    #pragma unroll
    for (int i = 0; i < 8; ++i) a[i] = make_float4(0.f, 0.f, 0.f, 0.f);
    for (int kk = 0; kk < KC1; ++kk) {
        float4 w  = *(const float4*)(wp + (size_t)kk * N1);
        float4 xa = *(const float4*)&x_lds[kk][0];
        float4 xb = *(const float4*)&x_lds[kk][4];
        float xs[8] = {xa.x, xa.y, xa.z, xa.w, xb.x, xb.y, xb.z, xb.w};
        #pragma unroll
        for (int i = 0; i < 8; ++i) {
            a[i].x += xs[i] * w.x; a[i].y += xs[i] * w.y;
            a[i].z += xs[i] * w.z; a[i].w += xs[i] * w.w;
        }
    }
    float* p1 = ws + OFF_P1;
    #pragma unroll
    for (int i = 0; i < 8; ++i)
        *(float4*)(p1 + ((size_t)(s * BSZ + bq * 8 + i)) * N1 + n4 * 4) = a[i];
}

// Fused LSTM1-cell + LSTM2 (gates GEMM + cell). Block owns 2 batches. Grid 64 x 256.
__global__ __launch_bounds__(256) void l12B_kernel(float* __restrict__ ws, int t)
{
    __shared__ __align__(16) float g_lds[2][2048];   // gates1 (16 KB)
    __shared__ float h_lds[2][512];
    __shared__ float h2o[2][128];
    __shared__ __align__(16) float g2_lds[2][512];
    int B = blockIdx.x, tid = threadIdx.x;
    int b0 = B * 2;

    { // stage old h2
        int bi = tid >> 7, j = tid & 127;
        h2o[bi][j] = ws[OFF_H2 + (b0 + bi) * 128 + j];
    }
    // reduce 16 k-split partials + bias -> gates1
    const float* p1 = ws + OFF_P1;
    #pragma unroll
    for (int q = 0; q < 4; ++q) {
        int s4 = tid + q * 256;          // 0..1023 float4-slots
        int bi = s4 >> 9, j4 = s4 & 511;
        float4 acc = *(const float4*)(ws + OFF_B1 + j4 * 4);
        #pragma unroll
        for (int sp = 0; sp < KS1; ++sp) {
            float4 p = *(const float4*)(p1 + ((size_t)(sp * BSZ + b0 + bi)) * N1 + j4 * 4);
            acc.x += p.x; acc.y += p.y; acc.z += p.z; acc.w += p.w;
        }
        *(float4*)&g_lds[bi][j4 * 4] = acc;
    }
    __syncthreads();
    // cell1 -> h1 (global for next step's l1A) + LDS
    #pragma unroll
    for (int q = 0; q < 4; ++q) {
        int slot = tid + q * 256;        // 0..1023
        int bi = slot >> 9, j = slot & 511;
        float gi = g_lds[bi][j],        gf = g_lds[bi][512 + j];
        float gg = g_lds[bi][1024 + j], go = g_lds[bi][1536 + j];
        int bj = (b0 + bi) * H1D + j;
        float c = sigf(gf) * ws[OFF_C1 + bj] + sigf(gi) * tanhf2(gg);
        ws[OFF_C1 + bj] = c;
        float h = sigf(go) * tanhf2(c);
        ws[OFF_H1 + bj] = h;
        h_lds[bi][j] = h;
    }
    __syncthreads();
    // gates2 GEMM: K = 512(h1) + 128(h2old), N = 512, per-thread 1 b x 4 n
    {
        int n4 = tid & 127, bi = tid >> 7;
        const float* wp = ws + OFF_WT2 + n4 * 4;
        float4 acc = *(const float4*)(ws + OFF_B2 + n4 * 4);
        for (int k = 0; k < 512; ++k) {
            float4 w = *(const float4*)(wp + (size_t)k * N2);
            float x = h_lds[bi][k];
            acc.x += x * w.x; acc.y += x * w.y; acc.z += x * w.z; acc.w += x * w.w;
        }
        for (int k = 0; k < 128; ++k) {
            float4 w = *(const float4*)(wp + (size_t)(512 + k) * N2);
            float x = h2o[bi][k];
            acc.x += x * w.x; acc.y += x * w.y; acc.z += x * w.z; acc.w += x * w.w;
        }
        *(float4*)&g2_lds[bi][n4 * 4] = acc;
    }
    __syncthreads();
    // cell2 -> h2 + history
    {
        int bi = tid >> 7, j = tid & 127;
        float gi = g2_lds[bi][j],       gf = g2_lds[bi][128 + j];
        float gg = g2_lds[bi][256 + j], go = g2_lds[bi][384 + j];
        int bj = (b0 + bi) * 128 + j;
        float c = sigf(gf) * ws[OFF_C2 + bj] + sigf(gi) * tanhf2(gg);
        ws[OFF_C2 + bj] = c;
        float h = sigf(go) * tanhf2(c);
        ws[OFF_H2 + bj] = h;
        ws[OFF_H2H + (size_t)t * (BSZ * 128) + bj] = h;
    }
}

// Attention pass 1 (flash partials). Grid (16,128) x 256. float4 loads, 2 rows/wave.
__global__ __launch_bounds__(256, 4) void attn1_kernel(
    const float* __restrict__ keys, const float* __restrict__ values,
    const int* __restrict__ lens, float* __restrict__ ws)
{
    __shared__ __align__(16) float s_h2[128];
    __shared__ float s_e[128];
    __shared__ float s_m[1];
    __shared__ __align__(16) float s_cp[512];
    int split = blockIdx.x, b = blockIdx.y, tid = threadIdx.x;
    int t0 = split * 128;
    if (tid < 128) s_h2[tid] = ws[OFF_H2 + b * 128 + tid];
    __syncthreads();

    int wave = tid >> 6, hf = (tid >> 5) & 1, l5 = tid & 31;
    int lb = lens[b];
    float4 hv = *(const float4*)&s_h2[l5 * 4];

    const float* kp = keys + (size_t)t0 * 16384 + b * 128 + l5 * 4;
    #pragma unroll 4
    for (int i = 0; i < 16; ++i) {
        int r = wave * 32 + i * 2 + hf;
        float4 kv = *(const float4*)(kp + (size_t)r * 16384);
        float p = kv.x * hv.x + kv.y * hv.y + kv.z * hv.z + kv.w * hv.w;
        p += __shfl_xor(p, 16);
        p += __shfl_xor(p, 8);
        p += __shfl_xor(p, 4);
        p += __shfl_xor(p, 2);
        p += __shfl_xor(p, 1);
        if (l5 == 0) s_e[r] = (t0 + r >= lb) ? -1e9f : p;
    }
    __syncthreads();
    if (tid < 64) {
        float m = fmaxf(s_e[tid], s_e[tid + 64]);
        m = fmaxf(m, __shfl_down(m, 32));
        m = fmaxf(m, __shfl_down(m, 16));
        m = fmaxf(m, __shfl_down(m, 8));
        m = fmaxf(m, __shfl_down(m, 4));
        m = fmaxf(m, __shfl_down(m, 2));
        m = fmaxf(m, __shfl_down(m, 1));
        if (tid == 0) s_m[0] = m;
    }
    __syncthreads();
    float m = s_m[0];
    if (tid < 128) s_e[tid] = __expf(s_e[tid] - m);
    __syncthreads();
    if (tid < 64) {
        float ss = s_e[tid] + s_e[tid + 64];
        ss += __shfl_down(ss, 32);
        ss += __shfl_down(ss, 16);
        ss += __shfl_down(ss, 8);
        ss += __shfl_down(ss, 4);
        ss += __shfl_down(ss, 2);
        ss += __shfl_down(ss, 1);
        if (tid == 0) {
            ws[OFF_AM + b * NS + split] = m;
            ws[OFF_AS + b * NS + split] = ss;
        }
    }
    // partial ctx
    float4 acc = make_float4(0.f, 0.f, 0.f, 0.f);
    const float* vp = values + (size_t)t0 * 16384 + b * 128 + l5 * 4;
    #pragma unroll 4
    for (int i = 0; i < 16; ++i) {
        int r = wave * 32 + i * 2 + hf;
        float4 vv = *(const float4*)(vp + (size_t)r * 16384);
        float a = s_e[r];
        acc.x += a * vv.x; acc.y += a * vv.y; acc.z += a * vv.z; acc.w += a * vv.w;
    }
    acc.x += __shfl_down(acc.x, 32);
    acc.y += __shfl_down(acc.y, 32);
    acc.z += __shfl_down(acc.z, 32);
    acc.w += __shfl_down(acc.w, 32);
    if (hf == 0) *(float4*)&s_cp[wave * 128 + l5 * 4] = acc;
    __syncthreads();
    if (tid < 128) {
        float c_ = s_cp[tid] + s_cp[128 + tid] + s_cp[256 + tid] + s_cp[384 + tid];
        ws[OFF_AP + ((size_t)b * NS + split) * 128 + tid] = c_;
    }
}

// Final ctx combine for t = 255 (no following l1A). Grid 128 x 128.
__global__ __launch_bounds__(128) void ctxfin_kernel(float* __restrict__ ws)
{
    __shared__ float s_ms[NS], s_ss[NS];
    int b = blockIdx.x, tid = threadIdx.x;
    if (tid < NS) { s_ms[tid] = ws[OFF_AM + b * NS + tid]; s_ss[tid] = ws[OFF_AS + b * NS + tid]; }
    __syncthreads();
    float M = -3.4e38f;
    #pragma unroll
    for (int i = 0; i < NS; ++i) M = fmaxf(M, s_ms[i]);
    float Ts = 0.f, c_ = 0.f;
    #pragma unroll
    for (int i = 0; i < NS; ++i) {
        float w = __expf(s_ms[i] - M);
        Ts += s_ss[i] * w;
        c_ += w * ws[OFF_AP + ((size_t)b * NS + i) * 128 + tid];
    }
    ws[OFF_CXH + ((size_t)(TDEC - 1) * BSZ + b) * 128 + tid] = c_ / Ts;
}

// Batched output projection over all 256 steps: M=32768, N=1000(pad 1024), K=256.
// Grid 2048 x 256; block = 16 m-rows, thread = 4 n-cols.
__global__ __launch_bounds__(256) void predall_kernel(
    const float* __restrict__ ws, const float* __restrict__ blin,
    float* __restrict__ out)
{
    __shared__ __align__(16) float x_lds[256][16];
    int m0 = blockIdx.x * 16;
    int tid = threadIdx.x;
    const float* h2h = ws + OFF_H2H;
    const float* cxh = ws + OFF_CXH;
    #pragma unroll
    for (int q = 0; q < 4; ++q) {
        int s4 = tid + q * 256;          // 0..1023: mi in low bits -> 4-way LDS banks, 64B global chunks
        int mi = s4 & 15, kq = s4 >> 4;  // kq 0..63 float4 along K
        size_t row = (size_t)(m0 + mi) * 128;
        float4 v = (kq < 32) ? *(const float4*)(h2h + row + kq * 4)
                             : *(const float4*)(cxh + row + (kq - 32) * 4);
        x_lds[kq * 4 + 0][mi] = v.x;
        x_lds[kq * 4 + 1][mi] = v.y;
        x_lds[kq * 4 + 2][mi] = v.z;
        x_lds[kq * 4 + 3][mi] = v.w;
    }
    __syncthreads();
    float4 acc[16];
    #pragma unroll
    for (int i = 0; i < 16; ++i) acc[i] = make_float4(0.f, 0.f, 0.f, 0.f);
    const float* wl = ws + OFF_WLT + tid * 4;
    for (int k = 0; k < 256; ++k) {
        float4 w  = *(const float4*)(wl + (size_t)k * NPAD);
        float4 xa = *(const float4*)&x_lds[k][0];
        float4 xb = *(const float4*)&x_lds[k][4];
        float4 xc = *(const float4*)&x_lds[k][8];
        float4 xd = *(const float4*)&x_lds[k][12];
        float xs[16] = {xa.x, xa.y, xa.z, xa.w, xb.x, xb.y, xb.z, xb.w,
                        xc.x, xc.y, xc.z, xc.w, xd.x, xd.y, xd.z, xd.w};
        #pragma unroll
        for (int i = 0; i < 16; ++i) {
            acc[i].x += xs[i] * w.x; acc[i].y += xs[i] * w.y;
            acc[i].z += xs[i] * w.z; acc[i].w += xs[i] * w.w;
        }
    }
    if (tid < 250) {                     // n = tid*4 .. tid*4+3 < 1000
        float4 bl = *(const float4*)(blin + tid * 4);
        #pragma unroll
        for (int i = 0; i < 16; ++i) {
            int mm = m0 + i;
            int tt = mm >> 7, b = mm & 127;
            float4 o = acc[i];
            o.x += bl.x; o.y += bl.y; o.z += bl.z; o.w += bl.w;
            *(float4*)(out + ((size_t)b * TDEC + tt) * VOC + tid * 4) = o;
        }
    }
}

extern "C" void kernel_launch(void* const* d_in, const int* in_sizes, int n_in,
                              void* d_out, int out_size, void* d_ws, size_t ws_size,
                              hipStream_t stream)
{
    const float* keys   = (const float*)d_in[0];
    const float* values = (const float*)d_in[1];
    const int*   lens   = (const int*)d_in[2];
    const int*   text   = (const int*)d_in[3];
    const float* emb    = (const float*)d_in[4];
    const float* Wih1   = (const float*)d_in[5];
    const float* Whh1   = (const float*)d_in[6];
    const float* bih1   = (const float*)d_in[7];
    const float* bhh1   = (const float*)d_in[8];
    const float* Wih2   = (const float*)d_in[9];
    const float* Whh2   = (const float*)d_in[10];
    const float* bih2   = (const float*)d_in[11];
    const float* bhh2   = (const float*)d_in[12];
    const float* Wlin   = (const float*)d_in[13];
    const float* blin   = (const float*)d_in[14];
    float* ws  = (float*)d_ws;
    float* out = (float*)d_out;

    prep_kernel<<<PREP_ELEMS / 256, 256, 0, stream>>>(
        Wih1, Whh1, bih1, bhh1, Wih2, Whh2, bih2, bhh2, Wlin, ws);

    for (int t = 0; t < TDEC; ++t) {
        l1A_kernel<<<512, 256, 0, stream>>>(emb, text, ws, t);
        l12B_kernel<<<64, 256, 0, stream>>>(ws, t);
        attn1_kernel<<<dim3(NS, BSZ), 256, 0, stream>>>(keys, values, lens, ws);
    }
    ctxfin_kernel<<<BSZ, 128, 0, stream>>>(ws);
    predall_kernel<<<2048, 256, 0, stream>>>(ws, blin, out);
}

// Round 2
// 13663.194 us; speedup vs baseline: 3.0651x; 1.8331x over previous
//
#include <hip/hip_runtime.h>
#include <cstdint>

#define TENC 2048
#define TDEC 256
#define BSZ  128
#define HID  256
#define KEYD 128
#define VALD 128
#define H1D  512
#define N1   2048   // 4*H1D
#define N2   512    // 4*KEYD
#define VOC  1000
#define NPAD 1024
#define NS   16     // attention t-splits (2048/128)
#define KS1  16     // LSTM1 k-splits
#define KC1  56     // 896/16

// ---- workspace layout (float offsets) ----
#define OFF_WT1   0            // 896*2048  k-major [k][n]
#define OFF_WT2   1835008      // 640*512
#define OFF_WLT   2162688      // 256*1024 (n padded to 1024)
#define OFF_B1    2424832      // 2048
#define OFF_B2    2426880      // 512
#define OFF_H1    2427392      // 128*512
#define OFF_C1    2492928      // 128*512
#define OFF_H2    2558464      // 128*128
#define OFF_C2    2574848      // 128*128
#define OFF_P1    2591232      // 16*128*2048 k-split partials LSTM1
#define OFF_AM    6785536      // 128*16 attn local max
#define OFF_AS    6787584      // 128*16 attn local expsum
#define OFF_AP    6789632      // 128*16*128 attn partial ctx
#define OFF_H2H   7051776      // 256*128*128 h2 history
#define OFF_CXH   11246080     // 256*128*128 ctx history
#define OFF_KBF   15440384     // keys bf16: 33554432 ushorts = 16777216 floats
#define OFF_VBF   32217600     // values bf16
// total 48994816 floats = 196 MB

#define PREP_ELEMS 2591232

__device__ __forceinline__ float sigf(float x)   { return 1.0f / (1.0f + __expf(-x)); }
__device__ __forceinline__ float tanhf2(float x) { return 1.0f - 2.0f / (__expf(2.0f * x) + 1.0f); }

__device__ __forceinline__ unsigned short f2bf(float f) {   // RNE fp32 -> bf16
    unsigned int u = __float_as_uint(f);
    u += 0x7FFFu + ((u >> 16) & 1u);
    return (unsigned short)(u >> 16);
}
__device__ __forceinline__ float bf_lo(unsigned int u) { return __uint_as_float(u << 16); }
__device__ __forceinline__ float bf_hi(unsigned int u) { return __uint_as_float(u & 0xFFFF0000u); }

// One-time: transpose weights to k-major, fuse biases, zero states.
__global__ __launch_bounds__(256) void prep_kernel(
    const float* __restrict__ Wih1, const float* __restrict__ Whh1,
    const float* __restrict__ bih1, const float* __restrict__ bhh1,
    const float* __restrict__ Wih2, const float* __restrict__ Whh2,
    const float* __restrict__ bih2, const float* __restrict__ bhh2,
    const float* __restrict__ Wlin, float* __restrict__ ws)
{
    int i = blockIdx.x * 256 + threadIdx.x;
    if (i < 1835008) {                       // WT1[k][n]
        int k = i >> 11, n = i & 2047;
        ws[OFF_WT1 + i] = (k < 384) ? Wih1[n * 384 + k] : Whh1[n * 512 + (k - 384)];
        return;
    }
    i -= 1835008;
    if (i < 327680) {                        // WT2[k][n]
        int k = i >> 9, n = i & 511;
        ws[OFF_WT2 + i] = (k < 512) ? Wih2[n * 512 + k] : Whh2[n * 128 + (k - 512)];
        return;
    }
    i -= 327680;
    if (i < 262144) {                        // WlinT[k][n], n padded to 1024
        int k = i >> 10, n = i & 1023;
        ws[OFF_WLT + i] = (n < VOC) ? Wlin[n * 256 + k] : 0.0f;
        return;
    }
    i -= 262144;
    if (i < 2048) { ws[OFF_B1 + i] = bih1[i] + bhh1[i]; return; }
    i -= 2048;
    if (i < 512)  { ws[OFF_B2 + i] = bih2[i] + bhh2[i]; return; }
    i -= 512;
    if (i < 65536) { ws[OFF_H1 + i] = 0.0f; return; }
    i -= 65536;
    if (i < 65536) { ws[OFF_C1 + i] = 0.0f; return; }
    i -= 65536;
    if (i < 16384) { ws[OFF_H2 + i] = 0.0f; return; }
    i -= 16384;
    ws[OFF_C2 + i] = 0.0f;
}

// One-time: K/V fp32 -> bf16 (RNE). 16,777,216 threads, 4 elems each.
__global__ __launch_bounds__(256) void conv_kernel(
    const float* __restrict__ keys, const float* __restrict__ values,
    float* __restrict__ ws)
{
    int T = blockIdx.x * 256 + threadIdx.x;
    const float* src;
    unsigned short* dst;
    if (T < 8388608) {
        src = keys + (size_t)T * 4;
        dst = (unsigned short*)(ws + OFF_KBF) + (size_t)T * 4;
    } else {
        int T2 = T - 8388608;
        src = values + (size_t)T2 * 4;
        dst = (unsigned short*)(ws + OFF_VBF) + (size_t)T2 * 4;
    }
    float4 v = *(const float4*)src;
    ushort4 o;
    o.x = f2bf(v.x); o.y = f2bf(v.y); o.z = f2bf(v.z); o.w = f2bf(v.w);
    *(ushort4*)dst = o;
}

// LSTM1 gates partial GEMM + fused attn-combine prologue (ctx of step t-1).
// Grid 512 blocks x 256. Block B: bq = B>>5 (8 batches), slice = B&31 -> s = slice>>1, half = slice&1.
__global__ __launch_bounds__(256, 2) void l1A_kernel(
    const float* __restrict__ emb, const int* __restrict__ text,
    float* __restrict__ ws, int t)
{
    __shared__ float s_ms[8][16];
    __shared__ float s_ss[8][16];
    __shared__ __align__(16) float s_ctx[8][128];
    __shared__ __align__(16) float x_lds[KC1][8];
    __shared__ int   s_tok[8];

    int B = blockIdx.x;
    int bq    = B >> 5;
    int slice = B & 31;
    int s  = slice >> 1;
    int hf = slice & 1;
    int tid = threadIdx.x;
    int n4 = hf * 256 + tid;                 // 0..511

    if (tid < 8) s_tok[tid] = text[(bq * 8 + tid) * TDEC + t];

    // ---- ctx combine: merge 16 flash partials from attn1 of step t-1 ----
    if (t > 0) {
        if (tid < 128) {
            int bi = tid >> 4, i = tid & 15;
            s_ms[bi][i] = ws[OFF_AM + (bq * 8 + bi) * NS + i];
        } else {
            int q = tid - 128;
            int bi = q >> 4, i = q & 15;
            s_ss[bi][i] = ws[OFF_AS + (bq * 8 + bi) * NS + i];
        }
        __syncthreads();
        int bi = tid >> 5, d4 = tid & 31;
        float M = -3.4e38f;
        #pragma unroll
        for (int i = 0; i < NS; ++i) M = fmaxf(M, s_ms[bi][i]);
        float Ts = 0.f;
        float4 acc = make_float4(0.f, 0.f, 0.f, 0.f);
        const float* ap = ws + OFF_AP + ((size_t)(bq * 8 + bi) * NS) * 128 + d4 * 4;
        #pragma unroll
        for (int i = 0; i < NS; ++i) {
            float w = __expf(s_ms[bi][i] - M);
            Ts += s_ss[bi][i] * w;
            float4 p = *(const float4*)(ap + i * 128);
            acc.x += w * p.x; acc.y += w * p.y; acc.z += w * p.z; acc.w += w * p.w;
        }
        float inv = 1.0f / Ts;
        acc.x *= inv; acc.y *= inv; acc.z *= inv; acc.w *= inv;
        *(float4*)&s_ctx[bi][d4 * 4] = acc;
        if (slice == 0)   // one designated block per bq writes ctx history
            *(float4*)(ws + OFF_CXH + (((size_t)(t - 1)) * BSZ + bq * 8 + bi) * 128 + d4 * 4) = acc;
    } else {
        *(float4*)&s_ctx[tid >> 5][(tid & 31) * 4] = make_float4(0.f, 0.f, 0.f, 0.f);
    }
    __syncthreads();

    // ---- stage x tile [8 b][56 k] into LDS: emb | ctx | h1 ----
    {
        int k0 = s * KC1;
        for (int slot = tid; slot < KC1 * 8; slot += 256) {
            int kk = slot >> 3, bi = slot & 7;
            int k = k0 + kk;
            float v;
            if (k < 256)      v = emb[s_tok[bi] * HID + k];
            else if (k < 384) v = s_ctx[bi][k - 256];
            else              v = ws[OFF_H1 + (bq * 8 + bi) * H1D + (k - 384)];
            x_lds[kk][bi] = v;
        }
    }
    __syncthreads();

    // ---- main GEMM: 8 b x 4 n over 56 k ----
    const float* wp = ws + OFF_WT1 + (size_t)(s * KC1) * N1 + n4 * 4;
    float4 a[8];
    #pragma unroll
    for (int i = 0; i < 8; ++i) a[i] = make_float4(0.f, 0.f, 0.f, 0.f);
    for (int kk = 0; kk < KC1; ++kk) {
        float4 w  = *(const float4*)(wp + (size_t)kk * N1);
        float4 xa = *(const float4*)&x_lds[kk][0];
        float4 xb = *(const float4*)&x_lds[kk][4];
        float xs[8] = {xa.x, xa.y, xa.z, xa.w, xb.x, xb.y, xb.z, xb.w};
        #pragma unroll
        for (int i = 0; i < 8; ++i) {
            a[i].x += xs[i] * w.x; a[i].y += xs[i] * w.y;
            a[i].z += xs[i] * w.z; a[i].w += xs[i] * w.w;
        }
    }
    float* p1 = ws + OFF_P1;
    #pragma unroll
    for (int i = 0; i < 8; ++i)
        *(float4*)(p1 + ((size_t)(s * BSZ + bq * 8 + i)) * N1 + n4 * 4) = a[i];
}

// Fused LSTM1-cell + LSTM2. One batch per block, 512 threads. Grid 128.
__global__ __launch_bounds__(512) void l12B_kernel(float* __restrict__ ws, int t)
{
    __shared__ __align__(16) float g_lds[2048];     // gates1 for this batch
    __shared__ float h_lds[512];
    __shared__ float h2o[128];
    __shared__ __align__(16) float g2p[4][512];     // gates2 k-split partials
    int b = blockIdx.x, tid = threadIdx.x;

    if (tid < 128) h2o[tid] = ws[OFF_H2 + b * 128 + tid];

    // reduce 16 k-split partials + bias -> gates1 (512 float4 slots, 1/thread)
    {
        const float* p1 = ws + OFF_P1;
        float4 acc = *(const float4*)(ws + OFF_B1 + tid * 4);
        #pragma unroll
        for (int sp = 0; sp < KS1; ++sp) {
            float4 p = *(const float4*)(p1 + ((size_t)(sp * BSZ + b)) * N1 + tid * 4);
            acc.x += p.x; acc.y += p.y; acc.z += p.z; acc.w += p.w;
        }
        *(float4*)&g_lds[tid * 4] = acc;
    }
    __syncthreads();
    // cell1 -> h1 (global for next step's l1A) + LDS
    {
        int j = tid;                       // 0..511
        float gi = g_lds[j],        gf = g_lds[512 + j];
        float gg = g_lds[1024 + j], go = g_lds[1536 + j];
        int bj = b * H1D + j;
        float c = sigf(gf) * ws[OFF_C1 + bj] + sigf(gi) * tanhf2(gg);
        ws[OFF_C1 + bj] = c;
        float h = sigf(go) * tanhf2(c);
        ws[OFF_H1 + bj] = h;
        h_lds[j] = h;
    }
    __syncthreads();
    // gates2 GEMM: K = 512(h1) + 128(h2old), N = 512. thread = n4(128) x ks(4), 160 k each.
    {
        int n4 = tid & 127, ks = tid >> 7;
        const float* wp = ws + OFF_WT2 + n4 * 4;
        float4 acc = make_float4(0.f, 0.f, 0.f, 0.f);
        if (ks == 0) acc = *(const float4*)(ws + OFF_B2 + n4 * 4);
        int k0 = ks * 160;
        for (int k = k0; k < k0 + 160; ++k) {
            float4 w = *(const float4*)(wp + (size_t)k * N2);
            float x = (k < 512) ? h_lds[k] : h2o[k - 512];
            acc.x += x * w.x; acc.y += x * w.y; acc.z += x * w.z; acc.w += x * w.w;
        }
        *(float4*)&g2p[ks][n4 * 4] = acc;
    }
    __syncthreads();
    // combine + cell2 -> h2 + history
    if (tid < 128) {
        int j = tid;
        float gi = g2p[0][j]       + g2p[1][j]       + g2p[2][j]       + g2p[3][j];
        float gf = g2p[0][128 + j] + g2p[1][128 + j] + g2p[2][128 + j] + g2p[3][128 + j];
        float gg = g2p[0][256 + j] + g2p[1][256 + j] + g2p[2][256 + j] + g2p[3][256 + j];
        float go = g2p[0][384 + j] + g2p[1][384 + j] + g2p[2][384 + j] + g2p[3][384 + j];
        int bj = b * 128 + j;
        float c = sigf(gf) * ws[OFF_C2 + bj] + sigf(gi) * tanhf2(gg);
        ws[OFF_C2 + bj] = c;
        float h = sigf(go) * tanhf2(c);
        ws[OFF_H2 + bj] = h;
        ws[OFF_H2H + (size_t)t * (BSZ * 128) + bj] = h;
    }
}

// Attention pass 1 (flash partials), bf16 K/V. Grid (16,128) x 256.
// Row handled by 16 lanes x 8 bf16 each; 4 rows in flight per wave.
__global__ __launch_bounds__(256, 4) void attn1_kernel(
    const float* __restrict__ ws_ro, const int* __restrict__ lens,
    float* __restrict__ ws)
{
    __shared__ __align__(16) float s_h2[128];
    __shared__ float s_e[128];
    __shared__ float s_m[1];
    __shared__ __align__(16) float s_cp[4][128];
    int split = blockIdx.x, b = blockIdx.y, tid = threadIdx.x;
    int t0 = split * 128;
    if (tid < 128) s_h2[tid] = ws[OFF_H2 + b * 128 + tid];
    __syncthreads();

    int w = tid >> 6, l = tid & 63, l4 = l & 15, g = l >> 4;
    int lb = lens[b];
    float h[8];
    #pragma unroll
    for (int j = 0; j < 8; ++j) h[j] = s_h2[l4 * 8 + j];

    const unsigned short* kbf = (const unsigned short*)(ws_ro + OFF_KBF);
    const unsigned short* vbf = (const unsigned short*)(ws_ro + OFF_VBF);
    const unsigned short* kp = kbf + (size_t)t0 * 16384 + b * 128 + l4 * 8;
    #pragma unroll 2
    for (int it = 0; it < 8; ++it) {
        int r = w * 32 + it * 4 + g;
        uint4 kv = *(const uint4*)(kp + (size_t)r * 16384);
        float p;
        p  = bf_lo(kv.x) * h[0]; p += bf_hi(kv.x) * h[1];
        p += bf_lo(kv.y) * h[2]; p += bf_hi(kv.y) * h[3];
        p += bf_lo(kv.z) * h[4]; p += bf_hi(kv.z) * h[5];
        p += bf_lo(kv.w) * h[6]; p += bf_hi(kv.w) * h[7];
        p += __shfl_xor(p, 8);
        p += __shfl_xor(p, 4);
        p += __shfl_xor(p, 2);
        p += __shfl_xor(p, 1);
        if (l4 == 0) s_e[r] = (t0 + r >= lb) ? -1e9f : p;
    }
    __syncthreads();
    if (tid < 64) {
        float m = fmaxf(s_e[tid], s_e[tid + 64]);
        m = fmaxf(m, __shfl_down(m, 32));
        m = fmaxf(m, __shfl_down(m, 16));
        m = fmaxf(m, __shfl_down(m, 8));
        m = fmaxf(m, __shfl_down(m, 4));
        m = fmaxf(m, __shfl_down(m, 2));
        m = fmaxf(m, __shfl_down(m, 1));
        if (tid == 0) s_m[0] = m;
    }
    __syncthreads();
    float m = s_m[0];
    if (tid < 128) s_e[tid] = __expf(s_e[tid] - m);
    __syncthreads();
    if (tid < 64) {
        float ss = s_e[tid] + s_e[tid + 64];
        ss += __shfl_down(ss, 32);
        ss += __shfl_down(ss, 16);
        ss += __shfl_down(ss, 8);
        ss += __shfl_down(ss, 4);
        ss += __shfl_down(ss, 2);
        ss += __shfl_down(ss, 1);
        if (tid == 0) {
            ws[OFF_AM + b * NS + split] = m;
            ws[OFF_AS + b * NS + split] = ss;
        }
    }
    // partial ctx
    float acc[8];
    #pragma unroll
    for (int j = 0; j < 8; ++j) acc[j] = 0.f;
    const unsigned short* vp = vbf + (size_t)t0 * 16384 + b * 128 + l4 * 8;
    #pragma unroll 2
    for (int it = 0; it < 8; ++it) {
        int r = w * 32 + it * 4 + g;
        uint4 vv = *(const uint4*)(vp + (size_t)r * 16384);
        float a = s_e[r];
        acc[0] += a * bf_lo(vv.x); acc[1] += a * bf_hi(vv.x);
        acc[2] += a * bf_lo(vv.y); acc[3] += a * bf_hi(vv.y);
        acc[4] += a * bf_lo(vv.z); acc[5] += a * bf_hi(vv.z);
        acc[6] += a * bf_lo(vv.w); acc[7] += a * bf_hi(vv.w);
    }
    #pragma unroll
    for (int j = 0; j < 8; ++j) {
        acc[j] += __shfl_xor(acc[j], 16);
        acc[j] += __shfl_xor(acc[j], 32);
    }
    if (g == 0) {
        #pragma unroll
        for (int j = 0; j < 8; ++j) s_cp[w][l4 * 8 + j] = acc[j];
    }
    __syncthreads();
    if (tid < 128) {
        float c_ = s_cp[0][tid] + s_cp[1][tid] + s_cp[2][tid] + s_cp[3][tid];
        ws[OFF_AP + ((size_t)b * NS + split) * 128 + tid] = c_;
    }
}

// Final ctx combine for t = 255. Grid 128 x 128.
__global__ __launch_bounds__(128) void ctxfin_kernel(float* __restrict__ ws)
{
    __shared__ float s_ms[NS], s_ss[NS];
    int b = blockIdx.x, tid = threadIdx.x;
    if (tid < NS) { s_ms[tid] = ws[OFF_AM + b * NS + tid]; s_ss[tid] = ws[OFF_AS + b * NS + tid]; }
    __syncthreads();
    float M = -3.4e38f;
    #pragma unroll
    for (int i = 0; i < NS; ++i) M = fmaxf(M, s_ms[i]);
    float Ts = 0.f, c_ = 0.f;
    #pragma unroll
    for (int i = 0; i < NS; ++i) {
        float w = __expf(s_ms[i] - M);
        Ts += s_ss[i] * w;
        c_ += w * ws[OFF_AP + ((size_t)b * NS + i) * 128 + tid];
    }
    ws[OFF_CXH + ((size_t)(TDEC - 1) * BSZ + b) * 128 + tid] = c_ / Ts;
}

// Batched output projection: M=32768, N=1000(pad 1024), K=256. Grid 2048 x 256.
__global__ __launch_bounds__(256) void predall_kernel(
    const float* __restrict__ ws, const float* __restrict__ blin,
    float* __restrict__ out)
{
    __shared__ __align__(16) float x_lds[256][16];
    int m0 = blockIdx.x * 16;
    int tid = threadIdx.x;
    const float* h2h = ws + OFF_H2H;
    const float* cxh = ws + OFF_CXH;
    #pragma unroll
    for (int q = 0; q < 4; ++q) {
        int s4 = tid + q * 256;
        int mi = s4 & 15, kq = s4 >> 4;
        size_t row = (size_t)(m0 + mi) * 128;
        float4 v = (kq < 32) ? *(const float4*)(h2h + row + kq * 4)
                             : *(const float4*)(cxh + row + (kq - 32) * 4);
        x_lds[kq * 4 + 0][mi] = v.x;
        x_lds[kq * 4 + 1][mi] = v.y;
        x_lds[kq * 4 + 2][mi] = v.z;
        x_lds[kq * 4 + 3][mi] = v.w;
    }
    __syncthreads();
    float4 acc[16];
    #pragma unroll
    for (int i = 0; i < 16; ++i) acc[i] = make_float4(0.f, 0.f, 0.f, 0.f);
    const float* wl = ws + OFF_WLT + tid * 4;
    for (int k = 0; k < 256; ++k) {
        float4 w  = *(const float4*)(wl + (size_t)k * NPAD);
        float4 xa = *(const float4*)&x_lds[k][0];
        float4 xb = *(const float4*)&x_lds[k][4];
        float4 xc = *(const float4*)&x_lds[k][8];
        float4 xd = *(const float4*)&x_lds[k][12];
        float xs[16] = {xa.x, xa.y, xa.z, xa.w, xb.x, xb.y, xb.z, xb.w,
                        xc.x, xc.y, xc.z, xc.w, xd.x, xd.y, xd.z, xd.w};
        #pragma unroll
        for (int i = 0; i < 16; ++i) {
            acc[i].x += xs[i] * w.x; acc[i].y += xs[i] * w.y;
            acc[i].z += xs[i] * w.z; acc[i].w += xs[i] * w.w;
        }
    }
    if (tid < 250) {
        float4 bl = *(const float4*)(blin + tid * 4);
        #pragma unroll
        for (int i = 0; i < 16; ++i) {
            int mm = m0 + i;
            int tt = mm >> 7, b = mm & 127;
            float4 o = acc[i];
            o.x += bl.x; o.y += bl.y; o.z += bl.z; o.w += bl.w;
            *(float4*)(out + ((size_t)b * TDEC + tt) * VOC + tid * 4) = o;
        }
    }
}

extern "C" void kernel_launch(void* const* d_in, const int* in_sizes, int n_in,
                              void* d_out, int out_size, void* d_ws, size_t ws_size,
                              hipStream_t stream)
{
    const float* keys   = (const float*)d_in[0];
    const float* values = (const float*)d_in[1];
    const int*   lens   = (const int*)d_in[2];
    const int*   text   = (const int*)d_in[3];
    const float* emb    = (const float*)d_in[4];
    const float* Wih1   = (const float*)d_in[5];
    const float* Whh1   = (const float*)d_in[6];
    const float* bih1   = (const float*)d_in[7];
    const float* bhh1   = (const float*)d_in[8];
    const float* Wih2   = (const float*)d_in[9];
    const float* Whh2   = (const float*)d_in[10];
    const float* bih2   = (const float*)d_in[11];
    const float* bhh2   = (const float*)d_in[12];
    const float* Wlin   = (const float*)d_in[13];
    const float* blin   = (const float*)d_in[14];
    float* ws  = (float*)d_ws;
    float* out = (float*)d_out;

    prep_kernel<<<PREP_ELEMS / 256, 256, 0, stream>>>(
        Wih1, Whh1, bih1, bhh1, Wih2, Whh2, bih2, bhh2, Wlin, ws);
    conv_kernel<<<65536, 256, 0, stream>>>(keys, values, ws);

    for (int t = 0; t < TDEC; ++t) {
        l1A_kernel<<<512, 256, 0, stream>>>(emb, text, ws, t);
        l12B_kernel<<<128, 512, 0, stream>>>(ws, t);
        attn1_kernel<<<dim3(NS, BSZ), 256, 0, stream>>>(ws, lens, ws);
    }
    ctxfin_kernel<<<BSZ, 128, 0, stream>>>(ws);
    predall_kernel<<<2048, 256, 0, stream>>>(ws, blin, out);
}